// Round 2
// baseline (1229.864 us; speedup 1.0000x reference)
//
#include <hip/hip_runtime.h>

// cost volume via bf16 MFMA band-GEMM, no LDS.
// out[n,h,x,9*dh+dw] = (1/128) * sum_c f1[n,h,x,c] * f2[n,h+dh-4,x+dw-4,c]
// N=8 H=128 W=256 C=128. Threshold is bf16-floor (1.05e-2) -> bf16 inputs OK.

#define NN 8
#define HH 128
#define WW 256
#define CC 128

typedef __attribute__((ext_vector_type(8))) short bf16x8;   // MFMA A/B frag (4 VGPRs)
typedef __attribute__((ext_vector_type(4))) float f32x4;    // MFMA C/D frag

__device__ inline short f2bf(float f) {           // RNE fp32 -> bf16
    unsigned u = __builtin_bit_cast(unsigned, f);
    u += 0x7fff + ((u >> 16) & 1);
    return (short)(u >> 16);
}

__device__ inline bf16x8 pack8(float4 lo, float4 hi) {
    bf16x8 r;
    r[0] = f2bf(lo.x); r[1] = f2bf(lo.y); r[2] = f2bf(lo.z); r[3] = f2bf(lo.w);
    r[4] = f2bf(hi.x); r[5] = f2bf(hi.y); r[6] = f2bf(hi.z); r[7] = f2bf(hi.w);
    return r;
}

__global__ __launch_bounds__(256)
void cost_volume_mfma(const float* __restrict__ f1,
                      const float* __restrict__ f2,
                      float* __restrict__ out) {
    const int t    = threadIdx.x;
    const int wave = t >> 6;
    const int lane = t & 63;
    const int q    = lane >> 4;   // quad: k-chunk select in frags, row-group in C
    const int r16  = lane & 15;   // A/B frag row during load; C column in epilogue

    // XCD swizzle: blockIdx%8 pins a 16-row h-chunk per XCD -> f2 rows stay in
    // that XCD's 4MB L2 (working set 24 rows * 128KB = 3MB).
    int b = blockIdx.x;
    const int xcd = b & 7;
    int i = b >> 3;                 // 0..511
    const int wt = i & 3;           // 4 w-tiles of 64
    const int hl = (i >> 2) & 15;
    const int n  = i >> 6;          // 0..7
    const int h  = xcd * 16 + hl;
    const int x0 = wt * 64 + wave * 16;   // this wave's 16-pixel A-tile

    // ---- A fragments: load once from global, reuse across all 9 dh ----
    // A[m = lane&15][k = q*8 + j], k-steps c0 = {0,32,64,96}
    bf16x8 afrag[4];
    {
        const float* ap = f1 + ((size_t)(n * HH + h) * WW + x0 + r16) * CC + q * 8;
        #pragma unroll
        for (int ks = 0; ks < 4; ++ks) {
            float4 lo = *(const float4*)(ap + ks * 32);
            float4 hi = *(const float4*)(ap + ks * 32 + 4);
            afrag[ks] = pack8(lo, hi);
        }
    }

    // B windows: x2b = x0-4 (frag0) and x0+12 (frag1); row = x2b + (lane&15)
    const int xb0 = x0 - 4 + r16;
    const int xb1 = xb0 + 16;
    const bool v0 = (unsigned)xb0 < (unsigned)WW;   // zero-pad outside image
    const bool v1 = (unsigned)xb1 < (unsigned)WW;

    float* outp = out + ((size_t)(n * HH + h) * WW + x0) * 81;
    const float scale = 1.0f / 128.0f;
    const float4 z4 = make_float4(0.f, 0.f, 0.f, 0.f);

    for (int dh = 0; dh < 9; ++dh) {
        const int y = h + dh - 4;
        f32x4 acc0 = {0.f, 0.f, 0.f, 0.f};
        f32x4 acc1 = {0.f, 0.f, 0.f, 0.f};
        if (0 <= y && y < HH) {                       // workgroup-uniform branch
            const float* f2row = f2 + ((size_t)(n * HH + y) * WW) * CC;
            const float* bp0 = f2row + (size_t)xb0 * CC + q * 8;
            const float* bp1 = f2row + (size_t)xb1 * CC + q * 8;
            #pragma unroll
            for (int ks = 0; ks < 4; ++ks) {
                float4 l0 = v0 ? *(const float4*)(bp0 + ks * 32)     : z4;
                float4 h0 = v0 ? *(const float4*)(bp0 + ks * 32 + 4) : z4;
                float4 l1 = v1 ? *(const float4*)(bp1 + ks * 32)     : z4;
                float4 h1 = v1 ? *(const float4*)(bp1 + ks * 32 + 4) : z4;
                acc0 = __builtin_amdgcn_mfma_f32_16x16x32_bf16(afrag[ks], pack8(l0, h0), acc0, 0, 0, 0);
                acc1 = __builtin_amdgcn_mfma_f32_16x16x32_bf16(afrag[ks], pack8(l1, h1), acc1, 0, 0, 0);
            }
        }
        // ---- epilogue: band extraction ----
        // C layout (m89-verified): value reg r of lane holds D[m = q*4+r][n2 = lane&15]
        // frag0: x2 = x0-4+n2  -> dw = n2 - m      (valid 0..8)
        // frag1: x2 = x0+12+n2 -> dw = n2 - m + 16 (valid <=8; >=1 always)
        // Exactly one frag covers each (m, dw) pair; y-invalid rows store zeros.
        #pragma unroll
        for (int r = 0; r < 4; ++r) {
            const int m = q * 4 + r;
            float* op = outp + (size_t)m * 81 + dh * 9;
            const int dw0 = r16 - m;
            if (0 <= dw0 && dw0 <= 8) op[dw0] = acc0[r] * scale;
            const int dw1 = dw0 + 16;
            if (dw1 <= 8) op[dw1] = acc1[r] * scale;
        }
    }
}

extern "C" void kernel_launch(void* const* d_in, const int* in_sizes, int n_in,
                              void* d_out, int out_size, void* d_ws, size_t ws_size,
                              hipStream_t stream) {
    const float* f1 = (const float*)d_in[0];
    const float* f2 = (const float*)d_in[1];
    float* out = (float*)d_out;
    dim3 grid(NN * HH * 4);   // 4096 WGs: 8 n * 128 h * 4 w-tiles
    dim3 block(256);          // 4 waves, one 16-px A-tile each
    cost_volume_mfma<<<grid, block, 0, stream>>>(f1, f2, out);
}